// Round 19
// baseline (118.571 us; speedup 1.0000x reference)
//
#include <hip/hip_runtime.h>
#include <stdint.h>
#include <stddef.h>

typedef __attribute__((ext_vector_type(8))) short short8;
typedef __attribute__((ext_vector_type(4))) float f32x4;
typedef __attribute__((ext_vector_type(4))) unsigned uint4v;

__device__ inline unsigned short f2bf(float x) {
    unsigned u = __float_as_uint(x);
    unsigned r = (u + 0x7fffu + ((u >> 16) & 1u)) >> 16;
    return (unsigned short)r;
}

// Pack hi16(lo), hi16(hi) into one dword with a single v_perm_b32 (truncation).
__device__ inline unsigned pk2t(float lo, float hi) {
    return __builtin_amdgcn_perm(__float_as_uint(hi), __float_as_uint(lo), 0x07060302u);
}

// VALU-pipe cross-lane add via DPP (ctrl must be compile-time constant).
template <int CTRL>
__device__ inline float dpp_add(float v) {
    int t = __builtin_amdgcn_update_dpp(0, __float_as_int(v), CTRL, 0xF, 0xF, true);
    return v + __int_as_float(t);
}
// Sum across the 16 lanes of a row; every lane ends with the total.
__device__ inline float row16_sum(float v) {
    v = dpp_add<0xB1>(v);    // quad_perm [1,0,3,2]  (xor 1)
    v = dpp_add<0x4E>(v);    // quad_perm [2,3,0,1]  (xor 2)
    v = dpp_add<0x124>(v);   // row_ror:4
    v = dpp_add<0x128>(v);   // row_ror:8
    return v;
}

// ---------------- K1: node = mean(tf, axis=-1) + W1T pre-convert -----------
// MEASURED (R10 probe): ~40 us, ~6.7 TB/s = at HBM floor.
__global__ __launch_bounds__(256) void k1_mean(const float* __restrict__ tf,
                                               const float* __restrict__ W1,
                                               float* __restrict__ node,
                                               unsigned short* __restrict__ w1t_g) {
    if (blockIdx.x < 64) {
        int base = blockIdx.x * 512 + threadIdx.x * 2;
#pragma unroll
        for (int e = 0; e < 2; ++e) {
            int idx = base + e;
            int c = idx >> 7, k = idx & 127;
            int ch = c >> 7, n = c & 127;
            w1t_g[idx] = f2bf(W1[(size_t)ch * 16384 + (size_t)k * 128 + n]);
        }
    }
    int wave = (blockIdx.x * blockDim.x + threadIdx.x) >> 6;  // 0..32767
    int lane = threadIdx.x & 63;
    int half = lane >> 5;
    int c = lane & 31;
    const f32x4* tf4 = reinterpret_cast<const f32x4*>(tf);
    size_t base = (size_t)wave * 8 * 64;

    f32x4 v[8];
#pragma unroll
    for (int k = 0; k < 8; ++k) v[k] = __builtin_nontemporal_load(&tf4[base + (size_t)k * 64 + lane]);

    float s[8];
#pragma unroll
    for (int k = 0; k < 8; ++k) s[k] = (v[k][0] + v[k][1]) + (v[k][2] + v[k][3]);
#pragma unroll
    for (int m = 1; m <= 16; m <<= 1) {
#pragma unroll
        for (int k = 0; k < 8; ++k) s[k] += __shfl_xor(s[k], m);
    }
    if (c == 0) {
#pragma unroll
        for (int k = 0; k < 8; ++k) {
            int rp = wave * 8 + k;
            node[(size_t)rp * 2 + half] = s[k] * (1.0f / 128.0f);
        }
    }
}

// ---------------- K2: pi/pj projection (coalesced BT stage) ----------------
// Also: blocks 0..15 pre-convert W2T; block 100 zeroes the k3 counters.
__global__ __launch_bounds__(512) void k2_proj(const float* __restrict__ node,
                                               const unsigned short* __restrict__ w1t_g,
                                               const float* __restrict__ b1,
                                               const float* __restrict__ W2,
                                               float* __restrict__ pi,
                                               float* __restrict__ pj,
                                               unsigned short* __restrict__ w2t_g,
                                               unsigned* __restrict__ cnt) {
    const int LP = 136;
    __shared__ unsigned short A_lds[16 * LP];
    __shared__ unsigned short BT[128 * LP];
    __shared__ float b1s[128];

    int tid = threadIdx.x;
    int rblk = blockIdx.x >> 1;
    int half = blockIdx.x & 1;
    int r0 = rblk * 16;

    if (blockIdx.x < 16) {
        int idx = blockIdx.x * 512 + tid;   // 0..8191
        int m = idx >> 7, k = idx & 127;
        w2t_g[idx] = f2bf(W2[(size_t)k * 64 + m]);
    }
    if (blockIdx.x == 100 && tid < 64) cnt[tid] = 0;   // reset k3 completion counters

    {
        int row = tid >> 5;
        int c0 = (tid & 31) * 4;
        float4 v = *reinterpret_cast<const float4*>(node + (size_t)(r0 + row) * 128 + c0);
        unsigned wb[2];
        wb[0] = (unsigned)f2bf(v.x) | ((unsigned)f2bf(v.y) << 16);
        wb[1] = (unsigned)f2bf(v.z) | ((unsigned)f2bf(v.w) << 16);
        *reinterpret_cast<uint2*>(&A_lds[row * LP + c0]) = *reinterpret_cast<uint2*>(wb);
    }
    {
        int n = tid >> 2;
        int q = tid & 3;
        const uint4v* src = reinterpret_cast<const uint4v*>(w1t_g + ((size_t)(half * 128 + n) * 128 + q * 32));
        uint4v* dst = reinterpret_cast<uint4v*>(&BT[n * LP + q * 32]);
#pragma unroll
        for (int e = 0; e < 4; ++e) dst[e] = src[e];
    }
    if (tid < 128) b1s[tid] = b1[tid];
    __syncthreads();

    int w = tid >> 6;
    int l = tid & 63;
    int lr = l & 15;
    int lg = l >> 4;

    f32x4 acc = {0, 0, 0, 0};
#pragma unroll
    for (int ks = 0; ks < 4; ++ks) {
        int kb = ks * 32 + lg * 8;
        short8 afrag = *reinterpret_cast<const short8*>(&A_lds[lr * LP + kb]);
        short8 bfrag = *reinterpret_cast<const short8*>(&BT[(w * 16 + lr) * LP + kb]);
        acc = __builtin_amdgcn_mfma_f32_16x16x32_bf16(afrag, bfrag, acc, 0, 0, 0);
    }
    float* out = half ? pj : pi;
    int col = w * 16 + lr;
    float bias = half ? 0.0f : b1s[col];
#pragma unroll
    for (int r = 0; r < 4; ++r) {
        int row = r0 + lg * 4 + r;
        out[(size_t)row * 128 + col] = acc[r] + bias;
    }
}

// ---------------- K34: pairwise MLP + fused final epilogue -----------------
// Grid 512 = (b, it of 8 i's). After F writes, the 8th finisher block for
// batch b performs the symmetrize/normalize epilogue (threadfence pattern).
__global__ __launch_bounds__(256) void k34_mlp(const float* __restrict__ pi,
                                               const float* __restrict__ pj,
                                               const unsigned short* __restrict__ w2t_g,
                                               const float* __restrict__ b2,
                                               const float* __restrict__ W3,
                                               const float* __restrict__ b3,
                                               const float* __restrict__ ap,
                                               float* __restrict__ F,
                                               float* __restrict__ outp,
                                               unsigned* __restrict__ cnt) {
    const int LDA = 136;
    __shared__ unsigned short W2T[64 * LDA];
    __shared__ float pipb8[8][128];
    __shared__ float b2s[64], w3s[64];
    __shared__ float s[64][65];
    __shared__ int amLast;

    int tid = threadIdx.x;
    int b = blockIdx.x >> 3;
    int it = blockIdx.x & 7;
    int i0 = it * 8;

    int w = tid >> 6;
    int l = tid & 63;
    int lr = l & 15;
    int lg = l >> 4;

    float pjreg[32];
    {
        const float* pjrow = pj + (size_t)(b * 64 + w * 16 + lr) * 128;
#pragma unroll
        for (int ks = 0; ks < 4; ++ks) {
            float4 q0 = *reinterpret_cast<const float4*>(pjrow + ks * 32 + lg * 8);
            float4 q1 = *reinterpret_cast<const float4*>(pjrow + ks * 32 + lg * 8 + 4);
            pjreg[ks * 8 + 0] = q0.x; pjreg[ks * 8 + 1] = q0.y;
            pjreg[ks * 8 + 2] = q0.z; pjreg[ks * 8 + 3] = q0.w;
            pjreg[ks * 8 + 4] = q1.x; pjreg[ks * 8 + 5] = q1.y;
            pjreg[ks * 8 + 6] = q1.z; pjreg[ks * 8 + 7] = q1.w;
        }
    }
    {
        int row = tid >> 5;
        int c4 = tid & 31;
        float4 v = reinterpret_cast<const float4*>(pi + ((size_t)(b * 64 + i0 + row) * 128))[c4];
        reinterpret_cast<float4*>(&pipb8[row][0])[c4] = v;
    }
    {
        int m = tid >> 2;
        int q = tid & 3;
        const uint4v* src = reinterpret_cast<const uint4v*>(w2t_g + (size_t)m * 128 + q * 32);
        uint4v* dst = reinterpret_cast<uint4v*>(&W2T[m * LDA + q * 32]);
#pragma unroll
        for (int e = 0; e < 4; ++e) dst[e] = src[e];
    }
    if (tid < 64) {
        b2s[tid] = b2[tid];
        w3s[tid] = W3[tid];
    }
    float b3v = b3[0];
    __syncthreads();

    short8 bfr[4][4];
#pragma unroll
    for (int ks = 0; ks < 4; ++ks) {
        int kb = ks * 32 + lg * 8;
#pragma unroll
        for (int nt = 0; nt < 4; ++nt)
            bfr[ks][nt] = *reinterpret_cast<const short8*>(&W2T[(nt * 16 + lr) * LDA + kb]);
    }

#pragma unroll 2
    for (int il = 0; il < 8; ++il) {
        f32x4 acc0 = {0.f, 0.f, 0.f, 0.f};
        f32x4 acc1 = {0.f, 0.f, 0.f, 0.f};
        f32x4 acc2 = {0.f, 0.f, 0.f, 0.f};
        f32x4 acc3 = {0.f, 0.f, 0.f, 0.f};
        const float4* prow = reinterpret_cast<const float4*>(&pipb8[il][0]);
#pragma unroll
        for (int ks = 0; ks < 4; ++ks) {
            float4 pa = prow[ks * 8 + lg * 2];
            float4 pb = prow[ks * 8 + lg * 2 + 1];
            unsigned au[4];
            au[0] = pk2t(fmaxf(pa.x + pjreg[ks * 8 + 0], 0.0f),
                         fmaxf(pa.y + pjreg[ks * 8 + 1], 0.0f));
            au[1] = pk2t(fmaxf(pa.z + pjreg[ks * 8 + 2], 0.0f),
                         fmaxf(pa.w + pjreg[ks * 8 + 3], 0.0f));
            au[2] = pk2t(fmaxf(pb.x + pjreg[ks * 8 + 4], 0.0f),
                         fmaxf(pb.y + pjreg[ks * 8 + 5], 0.0f));
            au[3] = pk2t(fmaxf(pb.z + pjreg[ks * 8 + 6], 0.0f),
                         fmaxf(pb.w + pjreg[ks * 8 + 7], 0.0f));
            short8 afrag = *reinterpret_cast<short8*>(au);
            acc0 = __builtin_amdgcn_mfma_f32_16x16x32_bf16(afrag, bfr[ks][0], acc0, 0, 0, 0);
            acc1 = __builtin_amdgcn_mfma_f32_16x16x32_bf16(afrag, bfr[ks][1], acc1, 0, 0, 0);
            acc2 = __builtin_amdgcn_mfma_f32_16x16x32_bf16(afrag, bfr[ks][2], acc2, 0, 0, 0);
            acc3 = __builtin_amdgcn_mfma_f32_16x16x32_bf16(afrag, bfr[ks][3], acc3, 0, 0, 0);
        }
        float part[4] = {0.f, 0.f, 0.f, 0.f};
#pragma unroll
        for (int mt = 0; mt < 4; ++mt) {
            int m = mt * 16 + lr;
            float w3 = w3s[m];
            float bb = b2s[m];
            f32x4 a = (mt == 0) ? acc0 : (mt == 1) ? acc1 : (mt == 2) ? acc2 : acc3;
#pragma unroll
            for (int r = 0; r < 4; ++r) {
                float h = fmaxf(a[r] + bb, 0.0f);
                part[r] += h * w3;
            }
        }
#pragma unroll
        for (int r = 0; r < 4; ++r) part[r] = row16_sum(part[r]);
        if (lr == 0) {
#pragma unroll
            for (int r = 0; r < 4; ++r) {
                int j = w * 16 + lg * 4 + r;
                F[((size_t)b * 64 + i0 + il) * 64 + j] = part[r] + b3v;
            }
        }
    }

    // ---- fused epilogue: last finisher block for batch b does k4 ----
    __threadfence();                 // release this block's F writes device-wide
    __syncthreads();
    if (tid == 0) {
        unsigned prev = atomicAdd(&cnt[b], 1u);
        amLast = (prev == 7u);
    }
    __syncthreads();
    if (amLast) {
        __threadfence();             // acquire other blocks' F writes
        for (int idx = tid; idx < 4096; idx += 256) {
            s[idx >> 6][idx & 63] = F[(size_t)b * 4096 + idx];
        }
        __syncthreads();
        int lane = l;
#pragma unroll
        for (int itr = 0; itr < 16; ++itr) {
            int i = w + 4 * itr;
            float a_ij = ap[i * 64 + lane];
            float v = 0.5f * a_ij + 0.25f * (s[i][lane] + s[lane][i]);
            v = fmaxf(v, 0.0f);
            if (i == lane) v += 1.0f;
            float sum = v;
            sum += __shfl_xor(sum, 1);
            sum += __shfl_xor(sum, 2);
            sum += __shfl_xor(sum, 4);
            sum += __shfl_xor(sum, 8);
            sum += __shfl_xor(sum, 16);
            sum += __shfl_xor(sum, 32);
            outp[(size_t)b * 4096 + i * 64 + lane] = v / (sum + 1e-8f);
        }
    }
}

extern "C" void kernel_launch(void* const* d_in, const int* in_sizes, int n_in,
                              void* d_out, int out_size, void* d_ws, size_t ws_size,
                              hipStream_t stream) {
    const float* tf = (const float*)d_in[0];
    const float* ap = (const float*)d_in[1];
    const float* W1 = (const float*)d_in[2];
    const float* b1 = (const float*)d_in[3];
    const float* W2 = (const float*)d_in[4];
    const float* b2 = (const float*)d_in[5];
    const float* W3 = (const float*)d_in[6];
    const float* b3 = (const float*)d_in[7];
    float* out = (float*)d_out;

    char* ws = (char*)d_ws;
    float* node = (float*)(ws);                              // 2 MB
    float* pi   = (float*)(ws + (size_t)(2 << 20));          // 2 MB (pi + b1)
    float* pj   = (float*)(ws + (size_t)(4 << 20));          // 2 MB
    float* F    = (float*)(ws + (size_t)(6 << 20));          // 1 MB
    unsigned short* w2t_g = (unsigned short*)(ws + (size_t)(7 << 20));            // 16 KB
    unsigned short* w1t_g = (unsigned short*)(ws + (size_t)(7 << 20) + 65536);    // 64 KB
    unsigned* cnt = (unsigned*)(ws + (size_t)(7 << 20) + 131072);                 // 256 B

    k1_mean<<<8192, 256, 0, stream>>>(tf, W1, node, w1t_g);
    k2_proj<<<512, 512, 0, stream>>>(node, w1t_g, b1, W2, pi, pj, w2t_g, cnt);
    k34_mlp<<<512, 256, 0, stream>>>(pi, pj, w2t_g, b2, W3, b3, ap, F, out, cnt);
}

// Round 20
// 65.761 us; speedup vs baseline: 1.8031x; 1.8031x over previous
//
#include <hip/hip_runtime.h>
#include <stdint.h>
#include <stddef.h>

typedef __attribute__((ext_vector_type(8))) short short8;
typedef __attribute__((ext_vector_type(4))) float f32x4;
typedef __attribute__((ext_vector_type(4))) unsigned uint4v;

__device__ inline unsigned short f2bf(float x) {
    unsigned u = __float_as_uint(x);
    unsigned r = (u + 0x7fffu + ((u >> 16) & 1u)) >> 16;
    return (unsigned short)r;
}

// Pack hi16(lo), hi16(hi) into one dword with a single v_perm_b32 (truncation).
__device__ inline unsigned pk2t(float lo, float hi) {
    return __builtin_amdgcn_perm(__float_as_uint(hi), __float_as_uint(lo), 0x07060302u);
}

// VALU-pipe cross-lane add via DPP (ctrl must be compile-time constant).
template <int CTRL>
__device__ inline float dpp_add(float v) {
    int t = __builtin_amdgcn_update_dpp(0, __float_as_int(v), CTRL, 0xF, 0xF, true);
    return v + __int_as_float(t);
}
// Sum across the 16 lanes of a row; every lane ends with the total.
__device__ inline float row16_sum(float v) {
    v = dpp_add<0xB1>(v);    // quad_perm [1,0,3,2]  (xor 1)
    v = dpp_add<0x4E>(v);    // quad_perm [2,3,0,1]  (xor 2)
    v = dpp_add<0x124>(v);   // row_ror:4
    v = dpp_add<0x128>(v);   // row_ror:8
    return v;
}

// ---------------- K1: node = mean(tf, axis=-1) + W1T pre-convert -----------
// MEASURED (R10 probe): ~40 us, ~6.7 TB/s = at HBM floor.
__global__ __launch_bounds__(256) void k1_mean(const float* __restrict__ tf,
                                               const float* __restrict__ W1,
                                               float* __restrict__ node,
                                               unsigned short* __restrict__ w1t_g) {
    if (blockIdx.x < 64) {
        int base = blockIdx.x * 512 + threadIdx.x * 2;
#pragma unroll
        for (int e = 0; e < 2; ++e) {
            int idx = base + e;
            int c = idx >> 7, k = idx & 127;
            int ch = c >> 7, n = c & 127;
            w1t_g[idx] = f2bf(W1[(size_t)ch * 16384 + (size_t)k * 128 + n]);
        }
    }
    int wave = (blockIdx.x * blockDim.x + threadIdx.x) >> 6;  // 0..32767
    int lane = threadIdx.x & 63;
    int half = lane >> 5;
    int c = lane & 31;
    const f32x4* tf4 = reinterpret_cast<const f32x4*>(tf);
    size_t base = (size_t)wave * 8 * 64;

    f32x4 v[8];
#pragma unroll
    for (int k = 0; k < 8; ++k) v[k] = __builtin_nontemporal_load(&tf4[base + (size_t)k * 64 + lane]);

    float s[8];
#pragma unroll
    for (int k = 0; k < 8; ++k) s[k] = (v[k][0] + v[k][1]) + (v[k][2] + v[k][3]);
#pragma unroll
    for (int m = 1; m <= 16; m <<= 1) {
#pragma unroll
        for (int k = 0; k < 8; ++k) s[k] += __shfl_xor(s[k], m);
    }
    if (c == 0) {
#pragma unroll
        for (int k = 0; k < 8; ++k) {
            int rp = wave * 8 + k;
            node[(size_t)rp * 2 + half] = s[k] * (1.0f / 128.0f);
        }
    }
}

// ---------------- K2: pi/pj projection (coalesced BT stage) ----------------
// 512 blocks (16 rows x half) x 512 threads = 2 blocks/CU. BT staged with
// coalesced b128 loads from pre-converted w1t_g (L2-hot). Blocks 0..15 also
// pre-convert W2T (extra duty).
__global__ __launch_bounds__(512) void k2_proj(const float* __restrict__ node,
                                               const unsigned short* __restrict__ w1t_g,
                                               const float* __restrict__ b1,
                                               const float* __restrict__ W2,
                                               float* __restrict__ pi,
                                               float* __restrict__ pj,
                                               unsigned short* __restrict__ w2t_g) {
    const int LP = 136;
    __shared__ unsigned short A_lds[16 * LP];
    __shared__ unsigned short BT[128 * LP];
    __shared__ float b1s[128];

    int tid = threadIdx.x;
    int rblk = blockIdx.x >> 1;
    int half = blockIdx.x & 1;
    int r0 = rblk * 16;

    if (blockIdx.x < 16) {
        int idx = blockIdx.x * 512 + tid;   // 0..8191
        int m = idx >> 7, k = idx & 127;
        w2t_g[idx] = f2bf(W2[(size_t)k * 64 + m]);
    }

    // Stage A: 16 rows x 128 cols; thread -> row = t>>5, 4 cols
    {
        int row = tid >> 5;
        int c0 = (tid & 31) * 4;
        float4 v = *reinterpret_cast<const float4*>(node + (size_t)(r0 + row) * 128 + c0);
        unsigned wb[2];
        wb[0] = (unsigned)f2bf(v.x) | ((unsigned)f2bf(v.y) << 16);
        wb[1] = (unsigned)f2bf(v.z) | ((unsigned)f2bf(v.w) << 16);
        *reinterpret_cast<uint2*>(&A_lds[row * LP + c0]) = *reinterpret_cast<uint2*>(wb);
    }
    // Stage BT: coalesced from w1t_g; thread -> n = t>>2, q = t&3 (32 cols)
    {
        int n = tid >> 2;
        int q = tid & 3;
        const uint4v* src = reinterpret_cast<const uint4v*>(w1t_g + ((size_t)(half * 128 + n) * 128 + q * 32));
        uint4v* dst = reinterpret_cast<uint4v*>(&BT[n * LP + q * 32]);
#pragma unroll
        for (int e = 0; e < 4; ++e) dst[e] = src[e];
    }
    if (tid < 128) b1s[tid] = b1[tid];
    __syncthreads();

    int w = tid >> 6;      // 0..7 -> col-sixteenth
    int l = tid & 63;
    int lr = l & 15;
    int lg = l >> 4;

    f32x4 acc = {0, 0, 0, 0};
#pragma unroll
    for (int ks = 0; ks < 4; ++ks) {
        int kb = ks * 32 + lg * 8;
        short8 afrag = *reinterpret_cast<const short8*>(&A_lds[lr * LP + kb]);
        short8 bfrag = *reinterpret_cast<const short8*>(&BT[(w * 16 + lr) * LP + kb]);
        acc = __builtin_amdgcn_mfma_f32_16x16x32_bf16(afrag, bfrag, acc, 0, 0, 0);
    }
    float* out = half ? pj : pi;
    int col = w * 16 + lr;
    float bias = half ? 0.0f : b1s[col];
#pragma unroll
    for (int r = 0; r < 4; ++r) {
        int row = r0 + lg * 4 + r;
        out[(size_t)row * 128 + col] = acc[r] + bias;
    }
}

// ---------------- K3: pairwise MLP via MFMA (reg A-frags, full W2T hoist) --
// Grid 512 = (b, it of 8 i's). All 16 W2T fragments in regs; epilogue
// reduce via DPP (VALU pipe). In-loop LDS: 8 pipb b128 reads per il only.
__global__ __launch_bounds__(256) void k3_mlp(const float* __restrict__ pi,
                                              const float* __restrict__ pj,
                                              const unsigned short* __restrict__ w2t_g,
                                              const float* __restrict__ b2,
                                              const float* __restrict__ W3,
                                              const float* __restrict__ b3,
                                              float* __restrict__ F) {
    const int LDA = 136;
    __shared__ unsigned short W2T[64 * LDA];
    __shared__ float pipb8[8][128];
    __shared__ float b2s[64], w3s[64];

    int tid = threadIdx.x;
    int b = blockIdx.x >> 3;
    int it = blockIdx.x & 7;
    int i0 = it * 8;

    int w = tid >> 6;
    int l = tid & 63;
    int lr = l & 15;
    int lg = l >> 4;

    float pjreg[32];
    {
        const float* pjrow = pj + (size_t)(b * 64 + w * 16 + lr) * 128;
#pragma unroll
        for (int ks = 0; ks < 4; ++ks) {
            float4 q0 = *reinterpret_cast<const float4*>(pjrow + ks * 32 + lg * 8);
            float4 q1 = *reinterpret_cast<const float4*>(pjrow + ks * 32 + lg * 8 + 4);
            pjreg[ks * 8 + 0] = q0.x; pjreg[ks * 8 + 1] = q0.y;
            pjreg[ks * 8 + 2] = q0.z; pjreg[ks * 8 + 3] = q0.w;
            pjreg[ks * 8 + 4] = q1.x; pjreg[ks * 8 + 5] = q1.y;
            pjreg[ks * 8 + 6] = q1.z; pjreg[ks * 8 + 7] = q1.w;
        }
    }
    // pi rows i0..i0+7 -> LDS (8x128 f32); 256 threads x float4
    {
        int row = tid >> 5;
        int c4 = tid & 31;
        float4 v = reinterpret_cast<const float4*>(pi + ((size_t)(b * 64 + i0 + row) * 128))[c4];
        reinterpret_cast<float4*>(&pipb8[row][0])[c4] = v;
    }
    // W2T stage: coalesced b128 from w2t_g
    {
        int m = tid >> 2;
        int q = tid & 3;
        const uint4v* src = reinterpret_cast<const uint4v*>(w2t_g + (size_t)m * 128 + q * 32);
        uint4v* dst = reinterpret_cast<uint4v*>(&W2T[m * LDA + q * 32]);
#pragma unroll
        for (int e = 0; e < 4; ++e) dst[e] = src[e];
    }
    if (tid < 64) {
        b2s[tid] = b2[tid];
        w3s[tid] = W3[tid];
    }
    float b3v = b3[0];
    __syncthreads();

    // Hoist ALL W2T fragments (iteration-invariant): 16 x short8 = 64 VGPR
    short8 bfr[4][4];
#pragma unroll
    for (int ks = 0; ks < 4; ++ks) {
        int kb = ks * 32 + lg * 8;
#pragma unroll
        for (int nt = 0; nt < 4; ++nt)
            bfr[ks][nt] = *reinterpret_cast<const short8*>(&W2T[(nt * 16 + lr) * LDA + kb]);
    }

#pragma unroll 2
    for (int il = 0; il < 8; ++il) {
        f32x4 acc0 = {0.f, 0.f, 0.f, 0.f};
        f32x4 acc1 = {0.f, 0.f, 0.f, 0.f};
        f32x4 acc2 = {0.f, 0.f, 0.f, 0.f};
        f32x4 acc3 = {0.f, 0.f, 0.f, 0.f};
        const float4* prow = reinterpret_cast<const float4*>(&pipb8[il][0]);
#pragma unroll
        for (int ks = 0; ks < 4; ++ks) {
            float4 pa = prow[ks * 8 + lg * 2];
            float4 pb = prow[ks * 8 + lg * 2 + 1];
            unsigned au[4];
            au[0] = pk2t(fmaxf(pa.x + pjreg[ks * 8 + 0], 0.0f),
                         fmaxf(pa.y + pjreg[ks * 8 + 1], 0.0f));
            au[1] = pk2t(fmaxf(pa.z + pjreg[ks * 8 + 2], 0.0f),
                         fmaxf(pa.w + pjreg[ks * 8 + 3], 0.0f));
            au[2] = pk2t(fmaxf(pb.x + pjreg[ks * 8 + 4], 0.0f),
                         fmaxf(pb.y + pjreg[ks * 8 + 5], 0.0f));
            au[3] = pk2t(fmaxf(pb.z + pjreg[ks * 8 + 6], 0.0f),
                         fmaxf(pb.w + pjreg[ks * 8 + 7], 0.0f));
            short8 afrag = *reinterpret_cast<short8*>(au);
            acc0 = __builtin_amdgcn_mfma_f32_16x16x32_bf16(afrag, bfr[ks][0], acc0, 0, 0, 0);
            acc1 = __builtin_amdgcn_mfma_f32_16x16x32_bf16(afrag, bfr[ks][1], acc1, 0, 0, 0);
            acc2 = __builtin_amdgcn_mfma_f32_16x16x32_bf16(afrag, bfr[ks][2], acc2, 0, 0, 0);
            acc3 = __builtin_amdgcn_mfma_f32_16x16x32_bf16(afrag, bfr[ks][3], acc3, 0, 0, 0);
        }
        float part[4] = {0.f, 0.f, 0.f, 0.f};
#pragma unroll
        for (int mt = 0; mt < 4; ++mt) {
            int m = mt * 16 + lr;
            float w3 = w3s[m];
            float bb = b2s[m];
            f32x4 a = (mt == 0) ? acc0 : (mt == 1) ? acc1 : (mt == 2) ? acc2 : acc3;
#pragma unroll
            for (int r = 0; r < 4; ++r) {
                float h = fmaxf(a[r] + bb, 0.0f);
                part[r] += h * w3;
            }
        }
#pragma unroll
        for (int r = 0; r < 4; ++r) part[r] = row16_sum(part[r]);
        if (lr == 0) {
#pragma unroll
            for (int r = 0; r < 4; ++r) {
                int j = w * 16 + lg * 4 + r;
                F[((size_t)b * 64 + i0 + il) * 64 + j] = part[r] + b3v;
            }
        }
    }
}

// ---------------- K4: symmetrize + eye + row-normalize ----------------
// 128 blocks (2 per batch; each computes 32 rows, loads full F_b).
__global__ __launch_bounds__(512) void k4_final(const float* __restrict__ F,
                                                const float* __restrict__ ap,
                                                float* __restrict__ out) {
    __shared__ float s[64][65];
    int b = blockIdx.x >> 1;
    int rh = (blockIdx.x & 1) * 32;
    int tid = threadIdx.x;
    for (int idx = tid; idx < 4096; idx += 512) {
        s[idx >> 6][idx & 63] = F[(size_t)b * 4096 + idx];
    }
    __syncthreads();
    int wv = tid >> 6, lane = tid & 63;
#pragma unroll
    for (int itr = 0; itr < 4; ++itr) {
        int i = rh + wv * 4 + itr;
        float a_ij = ap[i * 64 + lane];
        float v = 0.5f * a_ij + 0.25f * (s[i][lane] + s[lane][i]);
        v = fmaxf(v, 0.0f);
        if (i == lane) v += 1.0f;
        float sum = v;
        sum += __shfl_xor(sum, 1);
        sum += __shfl_xor(sum, 2);
        sum += __shfl_xor(sum, 4);
        sum += __shfl_xor(sum, 8);
        sum += __shfl_xor(sum, 16);
        sum += __shfl_xor(sum, 32);
        out[(size_t)b * 4096 + i * 64 + lane] = v / (sum + 1e-8f);
    }
}

extern "C" void kernel_launch(void* const* d_in, const int* in_sizes, int n_in,
                              void* d_out, int out_size, void* d_ws, size_t ws_size,
                              hipStream_t stream) {
    const float* tf = (const float*)d_in[0];
    const float* ap = (const float*)d_in[1];
    const float* W1 = (const float*)d_in[2];
    const float* b1 = (const float*)d_in[3];
    const float* W2 = (const float*)d_in[4];
    const float* b2 = (const float*)d_in[5];
    const float* W3 = (const float*)d_in[6];
    const float* b3 = (const float*)d_in[7];
    float* out = (float*)d_out;

    char* ws = (char*)d_ws;
    float* node = (float*)(ws);                              // 2 MB
    float* pi   = (float*)(ws + (size_t)(2 << 20));          // 2 MB (pi + b1)
    float* pj   = (float*)(ws + (size_t)(4 << 20));          // 2 MB
    float* F    = (float*)(ws + (size_t)(6 << 20));          // 1 MB
    unsigned short* w2t_g = (unsigned short*)(ws + (size_t)(7 << 20));            // 16 KB
    unsigned short* w1t_g = (unsigned short*)(ws + (size_t)(7 << 20) + 65536);    // 64 KB

    k1_mean<<<8192, 256, 0, stream>>>(tf, W1, node, w1t_g);
    k2_proj<<<512, 512, 0, stream>>>(node, w1t_g, b1, W2, pi, pj, w2t_g);
    k3_mlp<<<512, 256, 0, stream>>>(pi, pj, w2t_g, b2, W3, b3, F);
    k4_final<<<128, 512, 0, stream>>>(F, ap, out);
}